// Round 6
// baseline (333.677 us; speedup 1.0000x reference)
//
#include <hip/hip_runtime.h>
#include <math.h>

#define B_SZ   1024
#define CDIM   768
#define POOL   100
#define COSEPS 1e-6f
#define NTHR   256
#define BATCH4 4096   // float4s per stolen batch = 16 * NTHR (64 KB)

typedef __attribute__((ext_vector_type(4))) float f32x4;

// ---- work-stealing batched copy: block grabs 64KB batches via atomicAdd ----
__device__ __forceinline__ void copy_steal(const f32x4* __restrict__ src,
                                           f32x4* __restrict__ dst,
                                           int b0, int b1,
                                           unsigned int* __restrict__ ctr,
                                           unsigned int* sbatch, int t) {
    for (;;) {
        if (t == 0) *sbatch = atomicAdd(ctr, 1u);
        __syncthreads();
        const int base = b0 + (int)(*sbatch);
        __syncthreads();
        if (base >= b1) return;
        const f32x4* s = src + (size_t)base * BATCH4 + t;
        f32x4*       d = dst + (size_t)base * BATCH4 + t;
        f32x4 v[16];
        #pragma unroll
        for (int j = 0; j < 16; ++j) v[j] = s[j * NTHR];
        #pragma unroll
        for (int j = 0; j < 16; ++j) d[j * NTHR] = v[j];
    }
}

// ---------------- K1: prep (blocks 0..99) then all steal copy [0,nb1) -------
__global__ __launch_bounds__(NTHR)
void k1_prep_copy(const float* __restrict__ A, const float* __restrict__ K,
                  float* __restrict__ W1, float* __restrict__ W2,
                  float* __restrict__ knorm,
                  const f32x4* __restrict__ src4, f32x4* __restrict__ dst4,
                  unsigned int* __restrict__ ctr, int nb1) {
    const int blk = blockIdx.x, t = threadIdx.x;
    __shared__ float red[NTHR];
    __shared__ unsigned int sbatch;

    if (blk < POOL) {
        const int k = blk;
        const float* Ar = A + (size_t)k * CDIM;
        const float* Kr = K + (size_t)k * CDIM;

        float m = -INFINITY;
        for (int d = t; d < CDIM; d += NTHR) m = fmaxf(m, Ar[d]);
        red[t] = m; __syncthreads();
        for (int s = 128; s > 0; s >>= 1) { if (t < s) red[t] = fmaxf(red[t], red[t + s]); __syncthreads(); }
        m = red[0]; __syncthreads();

        float sum = 0.f;
        for (int d = t; d < CDIM; d += NTHR) sum += expf(Ar[d] - m);
        red[t] = sum; __syncthreads();
        for (int s = 128; s > 0; s >>= 1) { if (t < s) red[t] += red[t + s]; __syncthreads(); }
        sum = red[0]; __syncthreads();
        const float inv = 1.0f / sum;

        float ksq = 0.f;
        for (int d = t; d < CDIM; d += NTHR) { float kv = Kr[d]; ksq += kv * kv; }
        red[t] = ksq; __syncthreads();
        for (int s = 128; s > 0; s >>= 1) { if (t < s) red[t] += red[t + s]; __syncthreads(); }
        if (t == 0) knorm[k] = fmaxf(sqrtf(red[0]), COSEPS);

        for (int d = t; d < CDIM; d += NTHR) {
            float a_sm = expf(Ar[d] - m) * inv;
            W1[(size_t)k * CDIM + d] = a_sm * Kr[d];
            W2[(size_t)k * CDIM + d] = a_sm * a_sm;
        }
        __syncthreads();
    }
    copy_steal(src4, dst4, 0, nb1, ctr, &sbatch, t);
}

// ---------------- K2: aq (1024 blocks, float4) + steal copy [nb1,nb2) -------
__global__ __launch_bounds__(NTHR)
void k2_aq_copy(const float* __restrict__ xq,
                const float* __restrict__ W1, const float* __restrict__ W2,
                const float* __restrict__ knorm, float* __restrict__ aq,
                const f32x4* __restrict__ src4, f32x4* __restrict__ dst4,
                unsigned int* __restrict__ ctr, int nb1, int nb2) {
    const int blk = blockIdx.x, t = threadIdx.x;
    const int role = (blk >> 3) & 1;                // both roles on every XCD
    const int id   = ((blk >> 4) << 3) | (blk & 7); // 0..1023 per role
    __shared__ unsigned int sbatch;

    if (!role) {  // compute aq for b = id, then join copy
        __shared__ f32x4 xs4[CDIM / 4];
        const int b = id;
        const f32x4* xq4 = (const f32x4*)(xq + (size_t)b * CDIM);
        for (int i = t; i < CDIM / 4; i += NTHR) xs4[i] = xq4[i];
        __syncthreads();

        const int wave = t >> 6, lane = t & 63;
        for (int k = wave; k < POOL; k += 4) {
            const f32x4* w14 = (const f32x4*)(W1 + (size_t)k * CDIM);
            const f32x4* w24 = (const f32x4*)(W2 + (size_t)k * CDIM);
            float s1 = 0.f, s2 = 0.f;
            #pragma unroll
            for (int i = 0; i < CDIM / 4 / 64; ++i) {   // 3 iters
                const int d4 = lane + i * 64;
                f32x4 x  = xs4[d4];
                f32x4 w1 = w14[d4];
                f32x4 w2 = w24[d4];
                s1 += x.x * w1.x + x.y * w1.y + x.z * w1.z + x.w * w1.w;
                s2 += x.x * x.x * w2.x + x.y * x.y * w2.y
                    + x.z * x.z * w2.z + x.w * x.w * w2.w;
            }
            for (int off = 32; off > 0; off >>= 1) {
                s1 += __shfl_down(s1, off);
                s2 += __shfl_down(s2, off);
            }
            if (lane == 0) {
                float an = fmaxf(sqrtf(s2), COSEPS);
                float v  = s1 / (an * knorm[k]);
                aq[(size_t)b * POOL + k] = (v + 1.0f) * 0.5f;
            }
        }
        __syncthreads();
    }
    copy_steal(src4, dst4, nb1, nb2, ctr, &sbatch, t);
}

// ---------------- K3: p-contraction (1024 blocks) + steal copy [nb2,NB) -----
__global__ __launch_bounds__(NTHR)
void k3_p_copy(const float* __restrict__ aq, const float* __restrict__ p,
               float* __restrict__ out,
               const f32x4* __restrict__ src4, f32x4* __restrict__ dst4,
               unsigned int* __restrict__ ctr, int nb2, int NB, int n4) {
    const int blk = blockIdx.x, t = threadIdx.x;
    const int role = (blk >> 3) & 1;
    const int id   = ((blk >> 4) << 3) | (blk & 7);
    __shared__ unsigned int sbatch;

    if (!role) {
        __shared__ float a_s[POOL * 8];
        const int l  = id & 7;
        const int bg = id >> 3;

        for (int i = t; i < POOL * 8; i += NTHR) {
            int bb = i & 7, k = i >> 3;
            a_s[i] = aq[(size_t)(bg * 8 + bb) * POOL + k];
        }
        __syncthreads();

        const float* pl = p + (size_t)l * POOL * CDIM + t;
        float acc[8][3];
        #pragma unroll
        for (int bb = 0; bb < 8; ++bb)
            #pragma unroll
            for (int j = 0; j < 3; ++j) acc[bb][j] = 0.f;

        for (int k = 0; k < POOL; ++k) {
            float p0 = pl[(size_t)k * CDIM];
            float p1 = pl[(size_t)k * CDIM + 256];
            float p2 = pl[(size_t)k * CDIM + 512];
            #pragma unroll
            for (int bb = 0; bb < 8; ++bb) {
                float a = a_s[k * 8 + bb];
                acc[bb][0] += a * p0;
                acc[bb][1] += a * p1;
                acc[bb][2] += a * p2;
            }
        }

        const size_t EK_SZ = (size_t)B_SZ * 4 * CDIM;
        #pragma unroll
        for (int bb = 0; bb < 8; ++bb) {
            int b = bg * 8 + bb;
            float* dst = (l < 4)
                ? out + (size_t)b * (4 * CDIM) + (size_t)l * CDIM
                : out + EK_SZ + (size_t)b * (4 * CDIM) + (size_t)(l - 4) * CDIM;
            dst[t]       = acc[bb][0];
            dst[t + 256] = acc[bb][1];
            dst[t + 512] = acc[bb][2];
        }
        __syncthreads();
    }
    copy_steal(src4, dst4, nb2, NB, ctr, &sbatch, t);

    // tail (n4 % BATCH4 float4s; 0 for actual shapes, guarded anyway)
    for (int i = NB * BATCH4 + blk * NTHR + t; i < n4; i += (int)gridDim.x * NTHR)
        dst4[i] = src4[i];
}

extern "C" void kernel_launch(void* const* d_in, const int* in_sizes, int n_in,
                              void* d_out, int out_size, void* d_ws, size_t ws_size,
                              hipStream_t stream) {
    const float* x_querry = (const float*)d_in[0];
    const float* x_block  = (const float*)d_in[1];
    const float* K        = (const float*)d_in[2];
    const float* A        = (const float*)d_in[3];
    const float* p        = (const float*)d_in[4];
    float* out = (float*)d_out;

    // workspace layout (floats)
    float* W1    = (float*)d_ws;                 // 100*768
    float* W2    = W1 + POOL * CDIM;             // 100*768
    float* knorm = W2 + POOL * CDIM;             // 100 (pad 128)
    float* aq    = knorm + 128;                  // 1024*100
    unsigned int* ctrs = (unsigned int*)(aq + (size_t)B_SZ * POOL); // 3 u32

    const size_t EK_SZ = (size_t)B_SZ * 4 * CDIM;
    const f32x4* src4 = (const f32x4*)x_block;
    f32x4* dst4 = (f32x4*)(out + 2 * EK_SZ);

    const int n4 = in_sizes[1] / 4;              // 38,731,776
    const int NB = n4 / BATCH4;                  // 9456 full 64KB batches
    int c23 = (int)(NB * 0.162f);                // ~16% each for K2/K3
    if (c23 < 0) c23 = 0;
    int nb1 = NB - 2 * c23;                      // K1 share (~67.5%)
    if (nb1 < 0) nb1 = 0;
    const int nb2 = nb1 + c23;

    hipMemsetAsync(ctrs, 0, 3 * sizeof(unsigned int), stream);

    k1_prep_copy<<<2048, NTHR, 0, stream>>>(A, K, W1, W2, knorm, src4, dst4,
                                            ctrs + 0, nb1);
    k2_aq_copy  <<<2048, NTHR, 0, stream>>>(x_querry, W1, W2, knorm, aq,
                                            src4, dst4, ctrs + 1, nb1, nb2);
    k3_p_copy   <<<2048, NTHR, 0, stream>>>(aq, p, out, src4, dst4,
                                            ctrs + 2, nb2, NB, n4);
}

// Round 7
// 324.927 us; speedup vs baseline: 1.0269x; 1.0269x over previous
//
#include <hip/hip_runtime.h>
#include <math.h>

#define B_SZ   1024
#define CDIM   768
#define POOL   100
#define COSEPS 1e-6f
#define NTHR   256
#define NBLK   1024   // 4 blocks/CU guaranteed resident -> spin barriers safe
#define NHALF  512

typedef __attribute__((ext_vector_type(4))) float f32x4;

// streaming copy: plain loads, non-temporal stores
__device__ __forceinline__ void copy_range(const f32x4* __restrict__ src,
                                           f32x4* __restrict__ dst,
                                           int lo, int hi, int cid, int t) {
    const int stride = NHALF * NTHR;
    #pragma unroll 4
    for (int i = lo + cid * NTHR + t; i < hi; i += stride) {
        f32x4 v = src[i];
        __builtin_nontemporal_store(v, dst + i);
    }
}

// device-scope barrier among resident blocks (contributors add 1; all wait)
__device__ __forceinline__ void gbar(unsigned int* ctr, unsigned int target,
                                     bool contribute, int t) {
    __syncthreads();                       // drains this block's vmem before fence
    if (t == 0) {
        if (contribute) {
            __threadfence();               // release: make W/aq visible device-wide
            atomicAdd(ctr, 1u);
        }
        while (__hip_atomic_load(ctr, __ATOMIC_RELAXED, __HIP_MEMORY_SCOPE_AGENT)
               < target)
            __builtin_amdgcn_s_sleep(16);
        __threadfence();                   // acquire
    }
    __syncthreads();
}

__global__ __launch_bounds__(NTHR, 4)
void fused_all(const float* __restrict__ xq, const f32x4* __restrict__ src4,
               const float* __restrict__ Kp, const float* __restrict__ Ap,
               const float* __restrict__ pp, float* __restrict__ out,
               float* __restrict__ W1, float* __restrict__ W2,
               float* __restrict__ knorm, float* __restrict__ aq,
               unsigned int* __restrict__ ctrs,
               f32x4* __restrict__ dst4, int S, int n4)
{
    const int blk = blockIdx.x, t = threadIdx.x;
    const int role = blk & 1;              // 0 = copy, 1 = compute  (both on every XCD)
    const int id   = blk >> 1;             // 0..511
    __shared__ __align__(16) float smem[800];

    if (role == 0) {                       // pure copy half: [0, S)
        copy_range(src4, dst4, 0, S, id, t);
        return;
    }

    // ---------------- prep: ids 0..99, k = id -------------------------------
    if (id < POOL) {
        float* red = smem;
        const int k = id;
        const float* Ar = Ap + (size_t)k * CDIM;
        const float* Kr = Kp + (size_t)k * CDIM;

        float m = -INFINITY;
        for (int d = t; d < CDIM; d += NTHR) m = fmaxf(m, Ar[d]);
        red[t] = m; __syncthreads();
        for (int s = 128; s > 0; s >>= 1) { if (t < s) red[t] = fmaxf(red[t], red[t + s]); __syncthreads(); }
        m = red[0]; __syncthreads();

        float sum = 0.f;
        for (int d = t; d < CDIM; d += NTHR) sum += expf(Ar[d] - m);
        red[t] = sum; __syncthreads();
        for (int s = 128; s > 0; s >>= 1) { if (t < s) red[t] += red[t + s]; __syncthreads(); }
        sum = red[0]; __syncthreads();
        const float inv = 1.0f / sum;

        float ksq = 0.f;
        for (int d = t; d < CDIM; d += NTHR) { float kv = Kr[d]; ksq += kv * kv; }
        red[t] = ksq; __syncthreads();
        for (int s = 128; s > 0; s >>= 1) { if (t < s) red[t] += red[t + s]; __syncthreads(); }
        if (t == 0) knorm[k] = fmaxf(sqrtf(red[0]), COSEPS);

        for (int d = t; d < CDIM; d += NTHR) {
            float a_sm = expf(Ar[d] - m) * inv;
            W1[(size_t)k * CDIM + d] = a_sm * Kr[d];
            W2[(size_t)k * CDIM + d] = a_sm * a_sm;
        }
    }
    gbar(ctrs + 0, POOL, id < POOL, t);

    // ---------------- aq: b = id, id+512 ------------------------------------
    {
        f32x4* xs4 = (f32x4*)smem;
        #pragma unroll
        for (int rep = 0; rep < 2; ++rep) {
            const int b = id + rep * NHALF;
            __syncthreads();
            const f32x4* xq4 = (const f32x4*)(xq + (size_t)b * CDIM);
            for (int i = t; i < CDIM / 4; i += NTHR) xs4[i] = xq4[i];
            __syncthreads();

            const int wave = t >> 6, lane = t & 63;
            for (int k = wave; k < POOL; k += 4) {
                const f32x4* w14 = (const f32x4*)(W1 + (size_t)k * CDIM);
                const f32x4* w24 = (const f32x4*)(W2 + (size_t)k * CDIM);
                float s1 = 0.f, s2 = 0.f;
                #pragma unroll
                for (int i = 0; i < CDIM / 4 / 64; ++i) {   // 3 iters
                    const int d4 = lane + i * 64;
                    f32x4 x  = xs4[d4];
                    f32x4 w1 = w14[d4];
                    f32x4 w2 = w24[d4];
                    s1 += x.x * w1.x + x.y * w1.y + x.z * w1.z + x.w * w1.w;
                    s2 += x.x * x.x * w2.x + x.y * x.y * w2.y
                        + x.z * x.z * w2.z + x.w * x.w * w2.w;
                }
                for (int off = 32; off > 0; off >>= 1) {
                    s1 += __shfl_down(s1, off);
                    s2 += __shfl_down(s2, off);
                }
                if (lane == 0) {
                    float an = fmaxf(sqrtf(s2), COSEPS);
                    float v  = s1 / (an * knorm[k]);
                    aq[(size_t)b * POOL + k] = (v + 1.0f) * 0.5f;
                }
            }
        }
    }
    gbar(ctrs + 1, NHALF, true, t);

    // ---------------- p: units u = id, id+512 -------------------------------
    {
        float* a_s = smem;     // 800 floats
        #pragma unroll
        for (int rep = 0; rep < 2; ++rep) {
            const int u  = id + rep * NHALF;
            const int l  = u & 7;
            const int bg = u >> 3;
            __syncthreads();
            for (int i = t; i < POOL * 8; i += NTHR) {
                int bb = i & 7, k = i >> 3;
                a_s[i] = aq[(size_t)(bg * 8 + bb) * POOL + k];
            }
            __syncthreads();

            const float* pl = pp + (size_t)l * POOL * CDIM + t;
            float acc[8][3];
            #pragma unroll
            for (int bb = 0; bb < 8; ++bb)
                #pragma unroll
                for (int j = 0; j < 3; ++j) acc[bb][j] = 0.f;

            for (int k = 0; k < POOL; ++k) {
                float p0 = pl[(size_t)k * CDIM];
                float p1 = pl[(size_t)k * CDIM + 256];
                float p2 = pl[(size_t)k * CDIM + 512];
                #pragma unroll
                for (int bb = 0; bb < 8; ++bb) {
                    float a = a_s[k * 8 + bb];
                    acc[bb][0] += a * p0;
                    acc[bb][1] += a * p1;
                    acc[bb][2] += a * p2;
                }
            }

            const size_t EK_SZ = (size_t)B_SZ * 4 * CDIM;
            #pragma unroll
            for (int bb = 0; bb < 8; ++bb) {
                int b = bg * 8 + bb;
                float* dst = (l < 4)
                    ? out + (size_t)b * (4 * CDIM) + (size_t)l * CDIM
                    : out + EK_SZ + (size_t)b * (4 * CDIM) + (size_t)(l - 4) * CDIM;
                dst[t]       = acc[bb][0];
                dst[t + 256] = acc[bb][1];
                dst[t + 512] = acc[bb][2];
            }
        }
    }

    // ---------------- join copy: [S, n4) ------------------------------------
    copy_range(src4, dst4, S, n4, id, t);
}

extern "C" void kernel_launch(void* const* d_in, const int* in_sizes, int n_in,
                              void* d_out, int out_size, void* d_ws, size_t ws_size,
                              hipStream_t stream) {
    const float* x_querry = (const float*)d_in[0];
    const float* x_block  = (const float*)d_in[1];
    const float* K        = (const float*)d_in[2];
    const float* A        = (const float*)d_in[3];
    const float* p        = (const float*)d_in[4];
    float* out = (float*)d_out;

    // workspace layout (floats)
    float* W1    = (float*)d_ws;                 // 100*768
    float* W2    = W1 + POOL * CDIM;             // 100*768
    float* knorm = W2 + POOL * CDIM;             // 100 (pad 128)
    float* aq    = knorm + 128;                  // 1024*100
    unsigned int* ctrs = (unsigned int*)(aq + (size_t)B_SZ * POOL); // 2 u32

    const size_t EK_SZ = (size_t)B_SZ * 4 * CDIM;
    const f32x4* src4 = (const f32x4*)x_block;
    f32x4* dst4 = (f32x4*)(out + 2 * EK_SZ);

    const int n4 = in_sizes[1] / 4;
    int S = (int)((long long)n4 * 65 / 100) & ~1023;   // copy-half share, 16KB aligned

    hipMemsetAsync(ctrs, 0, 2 * sizeof(unsigned int), stream);
    fused_all<<<NBLK, NTHR, 0, stream>>>(x_querry, src4, K, A, p, out,
                                         W1, W2, knorm, aq, ctrs, dst4, S, n4);
}

// Round 8
// 304.908 us; speedup vs baseline: 1.0944x; 1.0657x over previous
//
#include <hip/hip_runtime.h>
#include <math.h>

#define B_SZ   1024
#define CDIM   768
#define POOL   100
#define COSEPS 1e-6f
#define NTHR   256
#define BATCH4 2048   // float4s per batch = 8 * NTHR (32 KB)

typedef __attribute__((ext_vector_type(4))) float f32x4;

// Batched copy: per batch, 8 guard-free 16B loads then 8 stores (plain).
__device__ __forceinline__ void copy_batches(const f32x4* __restrict__ src,
                                             f32x4* __restrict__ dst,
                                             int b0, int b1, int cid, int nblk, int t) {
    for (int bt = b0 + cid; bt < b1; bt += nblk) {
        const f32x4* s = src + (size_t)bt * BATCH4 + t;
        f32x4*       d = dst + (size_t)bt * BATCH4 + t;
        f32x4 v[8];
        #pragma unroll
        for (int j = 0; j < 8; ++j) v[j] = s[j * NTHR];
        #pragma unroll
        for (int j = 0; j < 8; ++j) d[j * NTHR] = v[j];
    }
}

// ---------------- K1: prep (blocks 0..99) + ALL blocks copy [0,nb1) ---------
__global__ __launch_bounds__(NTHR)
void k1_prep_copy(const float* __restrict__ A, const float* __restrict__ K,
                  float* __restrict__ W1, float* __restrict__ W2,
                  float* __restrict__ knorm,
                  const f32x4* __restrict__ src4, f32x4* __restrict__ dst4,
                  int nb1) {
    const int blk = blockIdx.x, t = threadIdx.x;
    if (blk < POOL) {
        __shared__ float red[NTHR];
        const int k = blk;
        const float* Ar = A + (size_t)k * CDIM;
        const float* Kr = K + (size_t)k * CDIM;

        float m = -INFINITY;
        for (int d = t; d < CDIM; d += NTHR) m = fmaxf(m, Ar[d]);
        red[t] = m; __syncthreads();
        for (int s = 128; s > 0; s >>= 1) { if (t < s) red[t] = fmaxf(red[t], red[t + s]); __syncthreads(); }
        m = red[0]; __syncthreads();

        float sum = 0.f;
        for (int d = t; d < CDIM; d += NTHR) sum += expf(Ar[d] - m);
        red[t] = sum; __syncthreads();
        for (int s = 128; s > 0; s >>= 1) { if (t < s) red[t] += red[t + s]; __syncthreads(); }
        sum = red[0]; __syncthreads();
        const float inv = 1.0f / sum;

        float ksq = 0.f;
        for (int d = t; d < CDIM; d += NTHR) { float kv = Kr[d]; ksq += kv * kv; }
        red[t] = ksq; __syncthreads();
        for (int s = 128; s > 0; s >>= 1) { if (t < s) red[t] += red[t + s]; __syncthreads(); }
        if (t == 0) knorm[k] = fmaxf(sqrtf(red[0]), COSEPS);

        for (int d = t; d < CDIM; d += NTHR) {
            float a_sm = expf(Ar[d] - m) * inv;
            W1[(size_t)k * CDIM + d] = a_sm * Kr[d];
            W2[(size_t)k * CDIM + d] = a_sm * a_sm;
        }
        __syncthreads();
    }
    // all 2048 blocks stride the same range; prep blocks join ~5us late
    copy_batches(src4, dst4, 0, nb1, blk, (int)gridDim.x, t);
}

// ---------------- K2: aq (1024 blocks) + copy [nb1,nb2); compute joins ------
__global__ __launch_bounds__(NTHR)
void k2_aq_copy(const float* __restrict__ xq,
                const float* __restrict__ W1, const float* __restrict__ W2,
                const float* __restrict__ knorm, float* __restrict__ aq,
                const f32x4* __restrict__ src4, f32x4* __restrict__ dst4,
                int nb1, int nbX, int nb2) {
    const int blk = blockIdx.x, t = threadIdx.x;
    const int role = (blk >> 3) & 1;                // both roles on every XCD
    const int id   = ((blk >> 4) << 3) | (blk & 7); // 0..1023 per role

    if (role) {                                     // copy-role: main sub-range
        copy_batches(src4, dst4, nb1, nbX, id, 1024, t);
        return;
    }

    __shared__ f32x4 xs4[CDIM / 4];
    const int b = id;
    const f32x4* xq4 = (const f32x4*)(xq + (size_t)b * CDIM);
    for (int i = t; i < CDIM / 4; i += NTHR) xs4[i] = xq4[i];
    __syncthreads();

    const int wave = t >> 6, lane = t & 63;
    for (int k = wave; k < POOL; k += 4) {
        const f32x4* w14 = (const f32x4*)(W1 + (size_t)k * CDIM);
        const f32x4* w24 = (const f32x4*)(W2 + (size_t)k * CDIM);
        float s1 = 0.f, s2 = 0.f;
        #pragma unroll
        for (int i = 0; i < CDIM / 4 / 64; ++i) {   // 3 iters
            const int d4 = lane + i * 64;
            f32x4 x  = xs4[d4];
            f32x4 w1 = w14[d4];
            f32x4 w2 = w24[d4];
            s1 += x.x * w1.x + x.y * w1.y + x.z * w1.z + x.w * w1.w;
            s2 += x.x * x.x * w2.x + x.y * x.y * w2.y
                + x.z * x.z * w2.z + x.w * x.w * w2.w;
        }
        for (int off = 32; off > 0; off >>= 1) {
            s1 += __shfl_down(s1, off);
            s2 += __shfl_down(s2, off);
        }
        if (lane == 0) {
            float an = fmaxf(sqrtf(s2), COSEPS);
            float v  = s1 / (an * knorm[k]);
            aq[(size_t)b * POOL + k] = (v + 1.0f) * 0.5f;
        }
    }
    __syncthreads();
    // join copy: tail sub-range of K2's share
    copy_batches(src4, dst4, nbX, nb2, id, 1024, t);
}

// ---------------- K3: p (1024 blocks) + copy [nb2,nbY); compute joins -------
__global__ __launch_bounds__(NTHR)
void k3_p_copy(const float* __restrict__ aq, const float* __restrict__ p,
               float* __restrict__ out,
               const f32x4* __restrict__ src4, f32x4* __restrict__ dst4,
               int nb2, int nbY, int NB, int n4) {
    const int blk = blockIdx.x, t = threadIdx.x;
    const int role = (blk >> 3) & 1;
    const int id   = ((blk >> 4) << 3) | (blk & 7);

    if (role) {
        copy_batches(src4, dst4, nb2, nbY, id, 1024, t);
        // tail: n4 % BATCH4 float4s (0 for actual shapes, guarded anyway)
        for (int i = NB * BATCH4 + id * NTHR + t; i < n4; i += 1024 * NTHR)
            dst4[i] = src4[i];
        return;
    }

    __shared__ float a_s[POOL * 8];
    const int l  = id & 7;
    const int bg = id >> 3;

    for (int i = t; i < POOL * 8; i += NTHR) {
        int bb = i & 7, k = i >> 3;
        a_s[i] = aq[(size_t)(bg * 8 + bb) * POOL + k];
    }
    __syncthreads();

    const float* pl = p + (size_t)l * POOL * CDIM + t;
    float acc[8][3];
    #pragma unroll
    for (int bb = 0; bb < 8; ++bb)
        #pragma unroll
        for (int j = 0; j < 3; ++j) acc[bb][j] = 0.f;

    for (int k = 0; k < POOL; ++k) {
        float p0 = pl[(size_t)k * CDIM];
        float p1 = pl[(size_t)k * CDIM + 256];
        float p2 = pl[(size_t)k * CDIM + 512];
        #pragma unroll
        for (int bb = 0; bb < 8; ++bb) {
            float a = a_s[k * 8 + bb];
            acc[bb][0] += a * p0;
            acc[bb][1] += a * p1;
            acc[bb][2] += a * p2;
        }
    }

    const size_t EK_SZ = (size_t)B_SZ * 4 * CDIM;
    #pragma unroll
    for (int bb = 0; bb < 8; ++bb) {
        int b = bg * 8 + bb;
        float* dst = (l < 4)
            ? out + (size_t)b * (4 * CDIM) + (size_t)l * CDIM
            : out + EK_SZ + (size_t)b * (4 * CDIM) + (size_t)(l - 4) * CDIM;
        dst[t]       = acc[bb][0];
        dst[t + 256] = acc[bb][1];
        dst[t + 512] = acc[bb][2];
    }
    __syncthreads();
    // join copy: tail sub-range of K3's share
    copy_batches(src4, dst4, nbY, NB, id, 1024, t);
}

extern "C" void kernel_launch(void* const* d_in, const int* in_sizes, int n_in,
                              void* d_out, int out_size, void* d_ws, size_t ws_size,
                              hipStream_t stream) {
    const float* x_querry = (const float*)d_in[0];
    const float* x_block  = (const float*)d_in[1];
    const float* K        = (const float*)d_in[2];
    const float* A        = (const float*)d_in[3];
    const float* p        = (const float*)d_in[4];
    float* out = (float*)d_out;

    // workspace layout (floats)
    float* W1    = (float*)d_ws;                 // 100*768
    float* W2    = W1 + POOL * CDIM;             // 100*768
    float* knorm = W2 + POOL * CDIM;             // 100 (pad 128)
    float* aq    = knorm + 128;                  // 1024*100

    const size_t EK_SZ = (size_t)B_SZ * 4 * CDIM;
    const f32x4* src4 = (const f32x4*)x_block;
    f32x4* dst4 = (f32x4*)(out + 2 * EK_SZ);

    const int n4 = in_sizes[1] / 4;              // 38,731,776
    const int NB = n4 / BATCH4;                  // 18,912 full 32KB batches

    // shares: K1 80% (full grid), K2 10%, K3 10%; compute joins last 25%
    const int nb1 = (int)((long long)NB * 80 / 100);
    const int k2s = (int)((long long)NB * 10 / 100);
    const int nb2 = nb1 + k2s;
    const int nbX = nb1 + (k2s * 3) / 4;         // copy-role part of K2
    const int nbY = nb2 + ((NB - nb2) * 3) / 4;  // copy-role part of K3

    k1_prep_copy<<<2048, NTHR, 0, stream>>>(A, K, W1, W2, knorm, src4, dst4, nb1);
    k2_aq_copy  <<<2048, NTHR, 0, stream>>>(x_querry, W1, W2, knorm, aq,
                                            src4, dst4, nb1, nbX, nb2);
    k3_p_copy   <<<2048, NTHR, 0, stream>>>(aq, p, out, src4, dst4,
                                            nb2, nbY, NB, n4);
}

// Round 9
// 272.744 us; speedup vs baseline: 1.2234x; 1.1179x over previous
//
#include <hip/hip_runtime.h>
#include <math.h>

#define B_SZ   1024
#define CDIM   768
#define POOL   100
#define COSEPS 1e-6f
#define NTHR   256
#define BATCH4 1024   // float4s per batch = 4 * NTHR (16 KB)

typedef __attribute__((ext_vector_type(4))) float f32x4;

// Software-pipelined copy: load batch N+1 while storing batch N.
// Static register names only (no dynamic indexing -> stays in VGPRs).
__device__ __forceinline__ void copy_pipe(const f32x4* __restrict__ src,
                                          f32x4* __restrict__ dst,
                                          int b0, int b1, int cid, int nblk, int t) {
    int btA = b0 + cid;
    if (btA >= b1) return;
    f32x4 va0, va1, va2, va3, vb0, vb1, vb2, vb3;
    {
        const f32x4* s = src + (size_t)btA * BATCH4 + t;
        va0 = s[0]; va1 = s[NTHR]; va2 = s[2 * NTHR]; va3 = s[3 * NTHR];
    }
    int btB = btA + nblk;
    while (btB < b1) {
        {   // issue loads for B
            const f32x4* s = src + (size_t)btB * BATCH4 + t;
            vb0 = s[0]; vb1 = s[NTHR]; vb2 = s[2 * NTHR]; vb3 = s[3 * NTHR];
        }
        {   // store A (compiler waits only on A's loads: counted vmcnt)
            f32x4* d = dst + (size_t)btA * BATCH4 + t;
            d[0] = va0; d[NTHR] = va1; d[2 * NTHR] = va2; d[3 * NTHR] = va3;
        }
        btA = btB; btB += nblk;
        if (btB >= b1) {
            f32x4* d = dst + (size_t)btA * BATCH4 + t;
            d[0] = vb0; d[NTHR] = vb1; d[2 * NTHR] = vb2; d[3 * NTHR] = vb3;
            return;
        }
        {
            const f32x4* s = src + (size_t)btB * BATCH4 + t;
            va0 = s[0]; va1 = s[NTHR]; va2 = s[2 * NTHR]; va3 = s[3 * NTHR];
        }
        {
            f32x4* d = dst + (size_t)btA * BATCH4 + t;
            d[0] = vb0; d[NTHR] = vb1; d[2 * NTHR] = vb2; d[3 * NTHR] = vb3;
        }
        btA = btB; btB += nblk;
    }
    {
        f32x4* d = dst + (size_t)btA * BATCH4 + t;
        d[0] = va0; d[NTHR] = va1; d[2 * NTHR] = va2; d[3 * NTHR] = va3;
    }
}

// ---------------- K1: prep (blocks 0..99) + copy batches [0,nb1) ------------
__global__ __launch_bounds__(NTHR)
void k1_prep_copy(const float* __restrict__ A, const float* __restrict__ K,
                  float* __restrict__ W1, float* __restrict__ W2,
                  float* __restrict__ knorm,
                  const f32x4* __restrict__ src4, f32x4* __restrict__ dst4,
                  int nb1) {
    const int blk = blockIdx.x, t = threadIdx.x;
    if (blk >= POOL) {
        copy_pipe(src4, dst4, 0, nb1, blk - POOL, (int)gridDim.x - POOL, t);
        return;
    }
    __shared__ float red[NTHR];
    const int k = blk;
    const float* Ar = A + (size_t)k * CDIM;
    const float* Kr = K + (size_t)k * CDIM;

    float m = -INFINITY;
    for (int d = t; d < CDIM; d += NTHR) m = fmaxf(m, Ar[d]);
    red[t] = m; __syncthreads();
    for (int s = 128; s > 0; s >>= 1) { if (t < s) red[t] = fmaxf(red[t], red[t + s]); __syncthreads(); }
    m = red[0]; __syncthreads();

    float sum = 0.f;
    for (int d = t; d < CDIM; d += NTHR) sum += expf(Ar[d] - m);
    red[t] = sum; __syncthreads();
    for (int s = 128; s > 0; s >>= 1) { if (t < s) red[t] += red[t + s]; __syncthreads(); }
    sum = red[0]; __syncthreads();
    const float inv = 1.0f / sum;

    float ksq = 0.f;
    for (int d = t; d < CDIM; d += NTHR) { float kv = Kr[d]; ksq += kv * kv; }
    red[t] = ksq; __syncthreads();
    for (int s = 128; s > 0; s >>= 1) { if (t < s) red[t] += red[t + s]; __syncthreads(); }
    if (t == 0) knorm[k] = fmaxf(sqrtf(red[0]), COSEPS);

    for (int d = t; d < CDIM; d += NTHR) {
        float a_sm = expf(Ar[d] - m) * inv;
        W1[(size_t)k * CDIM + d] = a_sm * Kr[d];
        W2[(size_t)k * CDIM + d] = a_sm * a_sm;
    }
}

// ---------------- K2: aq (1024 blocks) + copy batches [nb1,nb2) -------------
__global__ __launch_bounds__(NTHR)
void k2_aq_copy(const float* __restrict__ xq,
                const float* __restrict__ W1, const float* __restrict__ W2,
                const float* __restrict__ knorm, float* __restrict__ aq,
                const f32x4* __restrict__ src4, f32x4* __restrict__ dst4,
                int nb1, int nb2) {
    const int blk = blockIdx.x, t = threadIdx.x;
    const int role = (blk >> 3) & 1;                // both roles on every XCD
    const int id   = ((blk >> 4) << 3) | (blk & 7); // 0..1023 per role

    if (role) {
        copy_pipe(src4, dst4, nb1, nb2, id, 1024, t);
        return;
    }

    __shared__ f32x4 xs4[CDIM / 4];
    const int b = id;
    const f32x4* xq4 = (const f32x4*)(xq + (size_t)b * CDIM);
    for (int i = t; i < CDIM / 4; i += NTHR) xs4[i] = xq4[i];
    __syncthreads();

    const int wave = t >> 6, lane = t & 63;
    for (int k = wave; k < POOL; k += 4) {
        const f32x4* w14 = (const f32x4*)(W1 + (size_t)k * CDIM);
        const f32x4* w24 = (const f32x4*)(W2 + (size_t)k * CDIM);
        float s1 = 0.f, s2 = 0.f;
        #pragma unroll
        for (int i = 0; i < CDIM / 4 / 64; ++i) {   // 3 iters
            const int d4 = lane + i * 64;
            f32x4 x  = xs4[d4];
            f32x4 w1 = w14[d4];
            f32x4 w2 = w24[d4];
            s1 += x.x * w1.x + x.y * w1.y + x.z * w1.z + x.w * w1.w;
            s2 += x.x * x.x * w2.x + x.y * x.y * w2.y
                + x.z * x.z * w2.z + x.w * x.w * w2.w;
        }
        for (int off = 32; off > 0; off >>= 1) {
            s1 += __shfl_down(s1, off);
            s2 += __shfl_down(s2, off);
        }
        if (lane == 0) {
            float an = fmaxf(sqrtf(s2), COSEPS);
            float v  = s1 / (an * knorm[k]);
            aq[(size_t)b * POOL + k] = (v + 1.0f) * 0.5f;
        }
    }
}

// ---------------- K3: p-contraction (1024 blocks) + copy [nb2,NB) + tail ----
__global__ __launch_bounds__(NTHR)
void k3_p_copy(const float* __restrict__ aq, const float* __restrict__ p,
               float* __restrict__ out,
               const f32x4* __restrict__ src4, f32x4* __restrict__ dst4,
               int nb2, int NB, int n4) {
    const int blk = blockIdx.x, t = threadIdx.x;
    const int role = (blk >> 3) & 1;
    const int id   = ((blk >> 4) << 3) | (blk & 7);

    if (role) {
        copy_pipe(src4, dst4, nb2, NB, id, 1024, t);
        // tail: n4 % BATCH4 float4s (0 for actual shapes, guarded anyway)
        for (int i = NB * BATCH4 + id * NTHR + t; i < n4; i += 1024 * NTHR)
            dst4[i] = src4[i];
        return;
    }

    __shared__ float a_s[POOL * 8];
    const int l  = id & 7;
    const int bg = id >> 3;

    for (int i = t; i < POOL * 8; i += NTHR) {
        int bb = i & 7, k = i >> 3;
        a_s[i] = aq[(size_t)(bg * 8 + bb) * POOL + k];
    }
    __syncthreads();

    const float* pl = p + (size_t)l * POOL * CDIM + t;
    float acc[8][3];
    #pragma unroll
    for (int bb = 0; bb < 8; ++bb)
        #pragma unroll
        for (int j = 0; j < 3; ++j) acc[bb][j] = 0.f;

    for (int k = 0; k < POOL; ++k) {
        float p0 = pl[(size_t)k * CDIM];
        float p1 = pl[(size_t)k * CDIM + 256];
        float p2 = pl[(size_t)k * CDIM + 512];
        #pragma unroll
        for (int bb = 0; bb < 8; ++bb) {
            float a = a_s[k * 8 + bb];
            acc[bb][0] += a * p0;
            acc[bb][1] += a * p1;
            acc[bb][2] += a * p2;
        }
    }

    const size_t EK_SZ = (size_t)B_SZ * 4 * CDIM;
    #pragma unroll
    for (int bb = 0; bb < 8; ++bb) {
        int b = bg * 8 + bb;
        float* dst = (l < 4)
            ? out + (size_t)b * (4 * CDIM) + (size_t)l * CDIM
            : out + EK_SZ + (size_t)b * (4 * CDIM) + (size_t)(l - 4) * CDIM;
        dst[t]       = acc[bb][0];
        dst[t + 256] = acc[bb][1];
        dst[t + 512] = acc[bb][2];
    }
}

extern "C" void kernel_launch(void* const* d_in, const int* in_sizes, int n_in,
                              void* d_out, int out_size, void* d_ws, size_t ws_size,
                              hipStream_t stream) {
    const float* x_querry = (const float*)d_in[0];
    const float* x_block  = (const float*)d_in[1];
    const float* K        = (const float*)d_in[2];
    const float* A        = (const float*)d_in[3];
    const float* p        = (const float*)d_in[4];
    float* out = (float*)d_out;

    // workspace layout (floats)
    float* W1    = (float*)d_ws;                 // 100*768
    float* W2    = W1 + POOL * CDIM;             // 100*768
    float* knorm = W2 + POOL * CDIM;             // 100 (pad 128)
    float* aq    = knorm + 128;                  // 1024*100

    const size_t EK_SZ = (size_t)B_SZ * 4 * CDIM;
    const f32x4* src4 = (const f32x4*)x_block;
    f32x4* dst4 = (f32x4*)(out + 2 * EK_SZ);

    const int n4 = in_sizes[1] / 4;              // 38,731,776
    const int NB = n4 / BATCH4;                  // 37,824 full 16KB batches

    // R4's proven shares: 62.5% / 18.75% / 18.75%
    const int u16 = NB / 16;
    const int nb1 = u16 * 10;
    const int nb2 = u16 * 13;

    k1_prep_copy<<<2048, NTHR, 0, stream>>>(A, K, W1, W2, knorm, src4, dst4, nb1);
    k2_aq_copy  <<<2048, NTHR, 0, stream>>>(x_querry, W1, W2, knorm, aq,
                                            src4, dst4, nb1, nb2);
    k3_p_copy   <<<2048, NTHR, 0, stream>>>(aq, p, out, src4, dst4,
                                            nb2, NB, n4);
}

// Round 10
// 270.517 us; speedup vs baseline: 1.2335x; 1.0082x over previous
//
#include <hip/hip_runtime.h>
#include <math.h>

#define B_SZ   1024
#define CDIM   768
#define POOL   100
#define COSEPS 1e-6f
#define NTHR   256
#define BATCH4 2048   // float4s per batch = 8 * NTHR (32 KB)

typedef __attribute__((ext_vector_type(4))) float f32x4;

#define LOAD8(v, base)                                                       \
    do { const f32x4* _s = (base);                                           \
         v##0 = _s[0];        v##1 = _s[NTHR];     v##2 = _s[2 * NTHR];      \
         v##3 = _s[3 * NTHR]; v##4 = _s[4 * NTHR]; v##5 = _s[5 * NTHR];      \
         v##6 = _s[6 * NTHR]; v##7 = _s[7 * NTHR]; } while (0)
#define STORE8(v, base)                                                      \
    do { f32x4* _d = (base);                                                 \
         _d[0] = v##0;        _d[NTHR] = v##1;     _d[2 * NTHR] = v##2;      \
         _d[3 * NTHR] = v##3; _d[4 * NTHR] = v##4; _d[5 * NTHR] = v##5;      \
         _d[6 * NTHR] = v##6; _d[7 * NTHR] = v##7; } while (0)

// 2-deep software-pipelined copy, 8-wide bursts (32 KB batches).
// Static register names only; compiler emits counted vmcnt (never drains).
__device__ __forceinline__ void copy_pipe(const f32x4* __restrict__ src,
                                          f32x4* __restrict__ dst,
                                          int b0, int b1, int cid, int nblk, int t) {
    int btA = b0 + cid;
    if (btA >= b1) return;
    f32x4 va0, va1, va2, va3, va4, va5, va6, va7;
    f32x4 vb0, vb1, vb2, vb3, vb4, vb5, vb6, vb7;
    LOAD8(va, src + (size_t)btA * BATCH4 + t);
    int btB = btA + nblk;
    while (btB < b1) {
        LOAD8(vb, src + (size_t)btB * BATCH4 + t);
        STORE8(va, dst + (size_t)btA * BATCH4 + t);
        btA = btB; btB += nblk;
        if (btB >= b1) {
            STORE8(vb, dst + (size_t)btA * BATCH4 + t);
            return;
        }
        LOAD8(va, src + (size_t)btB * BATCH4 + t);
        STORE8(vb, dst + (size_t)btA * BATCH4 + t);
        btA = btB; btB += nblk;
    }
    STORE8(va, dst + (size_t)btA * BATCH4 + t);
}

// ---------------- K1: prep (blocks 0..99, then join) + copy [0,nb1) ---------
__global__ __launch_bounds__(NTHR)
void k1_prep_copy(const float* __restrict__ A, const float* __restrict__ K,
                  float* __restrict__ W1, float* __restrict__ W2,
                  float* __restrict__ knorm,
                  const f32x4* __restrict__ src4, f32x4* __restrict__ dst4,
                  int nb1) {
    const int blk = blockIdx.x, t = threadIdx.x;
    if (blk < POOL) {
        __shared__ float red[NTHR];
        const int k = blk;
        const float* Ar = A + (size_t)k * CDIM;
        const float* Kr = K + (size_t)k * CDIM;

        float m = -INFINITY;
        for (int d = t; d < CDIM; d += NTHR) m = fmaxf(m, Ar[d]);
        red[t] = m; __syncthreads();
        for (int s = 128; s > 0; s >>= 1) { if (t < s) red[t] = fmaxf(red[t], red[t + s]); __syncthreads(); }
        m = red[0]; __syncthreads();

        float sum = 0.f;
        for (int d = t; d < CDIM; d += NTHR) sum += expf(Ar[d] - m);
        red[t] = sum; __syncthreads();
        for (int s = 128; s > 0; s >>= 1) { if (t < s) red[t] += red[t + s]; __syncthreads(); }
        sum = red[0]; __syncthreads();
        const float inv = 1.0f / sum;

        float ksq = 0.f;
        for (int d = t; d < CDIM; d += NTHR) { float kv = Kr[d]; ksq += kv * kv; }
        red[t] = ksq; __syncthreads();
        for (int s = 128; s > 0; s >>= 1) { if (t < s) red[t] += red[t + s]; __syncthreads(); }
        if (t == 0) knorm[k] = fmaxf(sqrtf(red[0]), COSEPS);

        for (int d = t; d < CDIM; d += NTHR) {
            float a_sm = expf(Ar[d] - m) * inv;
            W1[(size_t)k * CDIM + d] = a_sm * Kr[d];
            W2[(size_t)k * CDIM + d] = a_sm * a_sm;
        }
        __syncthreads();
    }
    // all 2048 blocks stride the same range; prep blocks join ~5us late
    copy_pipe(src4, dst4, 0, nb1, blk, (int)gridDim.x, t);
}

// ---------------- K2: aq (1024 blocks) + copy batches [nb1,nb2) -------------
__global__ __launch_bounds__(NTHR)
void k2_aq_copy(const float* __restrict__ xq,
                const float* __restrict__ W1, const float* __restrict__ W2,
                const float* __restrict__ knorm, float* __restrict__ aq,
                const f32x4* __restrict__ src4, f32x4* __restrict__ dst4,
                int nb1, int nb2) {
    const int blk = blockIdx.x, t = threadIdx.x;
    const int role = (blk >> 3) & 1;                // both roles on every XCD
    const int id   = ((blk >> 4) << 3) | (blk & 7); // 0..1023 per role

    if (role) {
        copy_pipe(src4, dst4, nb1, nb2, id, 1024, t);
        return;
    }

    __shared__ f32x4 xs4[CDIM / 4];
    const int b = id;
    const f32x4* xq4 = (const f32x4*)(xq + (size_t)b * CDIM);
    for (int i = t; i < CDIM / 4; i += NTHR) xs4[i] = xq4[i];
    __syncthreads();

    const int wave = t >> 6, lane = t & 63;
    for (int k = wave; k < POOL; k += 4) {
        const f32x4* w14 = (const f32x4*)(W1 + (size_t)k * CDIM);
        const f32x4* w24 = (const f32x4*)(W2 + (size_t)k * CDIM);
        float s1 = 0.f, s2 = 0.f;
        #pragma unroll
        for (int i = 0; i < CDIM / 4 / 64; ++i) {   // 3 iters
            const int d4 = lane + i * 64;
            f32x4 x  = xs4[d4];
            f32x4 w1 = w14[d4];
            f32x4 w2 = w24[d4];
            s1 += x.x * w1.x + x.y * w1.y + x.z * w1.z + x.w * w1.w;
            s2 += x.x * x.x * w2.x + x.y * x.y * w2.y
                + x.z * x.z * w2.z + x.w * x.w * w2.w;
        }
        for (int off = 32; off > 0; off >>= 1) {
            s1 += __shfl_down(s1, off);
            s2 += __shfl_down(s2, off);
        }
        if (lane == 0) {
            float an = fmaxf(sqrtf(s2), COSEPS);
            float v  = s1 / (an * knorm[k]);
            aq[(size_t)b * POOL + k] = (v + 1.0f) * 0.5f;
        }
    }
}

// ---------------- K3: p-contraction (1024 blocks) + copy [nb2,NB) + tail ----
__global__ __launch_bounds__(NTHR)
void k3_p_copy(const float* __restrict__ aq, const float* __restrict__ p,
               float* __restrict__ out,
               const f32x4* __restrict__ src4, f32x4* __restrict__ dst4,
               int nb2, int NB, int n4) {
    const int blk = blockIdx.x, t = threadIdx.x;
    const int role = (blk >> 3) & 1;
    const int id   = ((blk >> 4) << 3) | (blk & 7);

    if (role) {
        copy_pipe(src4, dst4, nb2, NB, id, 1024, t);
        // tail: n4 % BATCH4 float4s (0 for actual shapes, guarded anyway)
        for (int i = NB * BATCH4 + id * NTHR + t; i < n4; i += 1024 * NTHR)
            dst4[i] = src4[i];
        return;
    }

    __shared__ float a_s[POOL * 8];
    const int l  = id & 7;
    const int bg = id >> 3;

    for (int i = t; i < POOL * 8; i += NTHR) {
        int bb = i & 7, k = i >> 3;
        a_s[i] = aq[(size_t)(bg * 8 + bb) * POOL + k];
    }
    __syncthreads();

    const float* pl = p + (size_t)l * POOL * CDIM + t;
    float acc[8][3];
    #pragma unroll
    for (int bb = 0; bb < 8; ++bb)
        #pragma unroll
        for (int j = 0; j < 3; ++j) acc[bb][j] = 0.f;

    for (int k = 0; k < POOL; ++k) {
        float p0 = pl[(size_t)k * CDIM];
        float p1 = pl[(size_t)k * CDIM + 256];
        float p2 = pl[(size_t)k * CDIM + 512];
        #pragma unroll
        for (int bb = 0; bb < 8; ++bb) {
            float a = a_s[k * 8 + bb];
            acc[bb][0] += a * p0;
            acc[bb][1] += a * p1;
            acc[bb][2] += a * p2;
        }
    }

    const size_t EK_SZ = (size_t)B_SZ * 4 * CDIM;
    #pragma unroll
    for (int bb = 0; bb < 8; ++bb) {
        int b = bg * 8 + bb;
        float* dst = (l < 4)
            ? out + (size_t)b * (4 * CDIM) + (size_t)l * CDIM
            : out + EK_SZ + (size_t)b * (4 * CDIM) + (size_t)(l - 4) * CDIM;
        dst[t]       = acc[bb][0];
        dst[t + 256] = acc[bb][1];
        dst[t + 512] = acc[bb][2];
    }
}

extern "C" void kernel_launch(void* const* d_in, const int* in_sizes, int n_in,
                              void* d_out, int out_size, void* d_ws, size_t ws_size,
                              hipStream_t stream) {
    const float* x_querry = (const float*)d_in[0];
    const float* x_block  = (const float*)d_in[1];
    const float* K        = (const float*)d_in[2];
    const float* A        = (const float*)d_in[3];
    const float* p        = (const float*)d_in[4];
    float* out = (float*)d_out;

    // workspace layout (floats)
    float* W1    = (float*)d_ws;                 // 100*768
    float* W2    = W1 + POOL * CDIM;             // 100*768
    float* knorm = W2 + POOL * CDIM;             // 100 (pad 128)
    float* aq    = knorm + 128;                  // 1024*100

    const size_t EK_SZ = (size_t)B_SZ * 4 * CDIM;
    const f32x4* src4 = (const f32x4*)x_block;
    f32x4* dst4 = (f32x4*)(out + 2 * EK_SZ);

    const int n4 = in_sizes[1] / 4;              // 38,731,776
    const int NB = n4 / BATCH4;                  // 18,912 full 32KB batches

    // R9's proven shares: 62.5% / 18.75% / 18.75%
    const int u16 = NB / 16;
    const int nb1 = u16 * 10;
    const int nb2 = u16 * 13;

    k1_prep_copy<<<2048, NTHR, 0, stream>>>(A, K, W1, W2, knorm, src4, dst4, nb1);
    k2_aq_copy  <<<2048, NTHR, 0, stream>>>(x_querry, W1, W2, knorm, aq,
                                            src4, dst4, nb1, nb2);
    k3_p_copy   <<<2048, NTHR, 0, stream>>>(aq, p, out, src4, dst4,
                                            nb2, NB, n4);
}